// Round 1
// 788.771 us; speedup vs baseline: 1.0388x; 1.0388x over previous
//
#include <hip/hip_runtime.h>
#include <hip/hip_fp16.h>

// N=1024, F=22, T=1000, H=64, gates 4H=256
// R11: R10 + serial-loop shortening.
//  - Input-half MFMAs (k<64 for L1/L2, k<32 for L0) hoisted BEFORE the tight
//    sibling poll: they depend only on cross-layer data with 3-tick lead.
//    Only the 2-deep recurrent MFMA chain remains on the critical path.
//  - Sibling flag read pre-issued before the input-half MFMAs; common path
//    skips the spin loop entirely (flag already >= t-1).
//  - Tight sibling spin has NO s_sleep (cross-layer amortized spins keep it).
//  - __threadfence_block -> s_waitcnt lgkmcnt(0) (LDS-release only).
// Protocol/leads/ring unchanged from R10 (audited: early reads are gated by
// the same cross-layer polls; ring overwriters are gated on the reader's OWN
// flag, which is written after the read -> early read is strictly safer).
// 896 threads = 14 waves: 0-3 L2, 4-7 L1, 8-11 L0, 12-13 x stager.
// Flags monotone tick counters: [0..3]=L2, [4..7]=L1, [8..11]=L0, [12..13]=ST.
#define TT 1000
#define FF 22
#define HH 64
#define BB 4
#define NBLK 256
#define S0 112
#define S1 144
#define SL0 (4 * S0)
#define SL1 (4 * S1)

typedef _Float16 half8 __attribute__((ext_vector_type(8)));
typedef float float4v __attribute__((ext_vector_type(4)));

__device__ __forceinline__ float sigm(float v) {
    return __builtin_amdgcn_rcpf(1.0f + __expf(-v));
}
__device__ __forceinline__ float tanh_(float v) {
    return 1.0f - 2.0f * __builtin_amdgcn_rcpf(__expf(2.0f * v) + 1.0f);
}

__device__ __forceinline__ float sel4(const float4v a, int q) {
    float lo = (q & 2) ? a[2] : a[0];
    float hi = (q & 2) ? a[3] : a[1];
    return (q & 1) ? hi : lo;
}

__device__ __forceinline__ float gate_update(const float z[4], float& c) {
    float cc = sigm(z[1]) * c + sigm(z[0]) * tanh_(z[2]);
    c = cc;
    return sigm(z[3]) * tanh_(cc);
}

__device__ __forceinline__ int ldmin4(const int* p) {
    int4 v = *(const int4*)p;
    return min(min(v.x, v.y), min(v.z, v.w));
}

// amortized cross-layer spin: keep s_sleep (fires every 4 ticks)
#define SPIN(cond) do { for (;;) { asm volatile("" ::: "memory"); if (cond) break; \
                        __builtin_amdgcn_s_sleep(1); } asm volatile("" ::: "memory"); } while (0)
// tight sibling spin: no sleep (detect latency is on the serial path)
#define SPINF(cond) do { for (;;) { asm volatile("" ::: "memory"); if (cond) break; \
                         } asm volatile("" ::: "memory"); } while (0)
// LDS release: drain LDS writes only (no vmcnt)
#define LFENCE() asm volatile("s_waitcnt lgkmcnt(0)" ::: "memory")

extern "C" __global__ void __launch_bounds__(896, 1)
lstm_fused(const float* __restrict__ x,
           const float* __restrict__ Wih0, const float* __restrict__ Whh0,
           const float* __restrict__ bih0, const float* __restrict__ bhh0,
           const float* __restrict__ Wih1, const float* __restrict__ Whh1,
           const float* __restrict__ bih1, const float* __restrict__ bhh1,
           const float* __restrict__ Wih2, const float* __restrict__ Whh2,
           const float* __restrict__ bih2, const float* __restrict__ bhh2,
           const float* __restrict__ w0, const float* __restrict__ b0,
           const float* __restrict__ w1, const float* __restrict__ b1,
           const float* __restrict__ w2, const float* __restrict__ b2,
           const float* __restrict__ w3, const float* __restrict__ b3,
           const float* __restrict__ g0, const float* __restrict__ be0,
           const float* __restrict__ m0, const float* __restrict__ v0,
           const float* __restrict__ g1, const float* __restrict__ be1,
           const float* __restrict__ m1, const float* __restrict__ v1,
           const float* __restrict__ g2, const float* __restrict__ be2,
           const float* __restrict__ m2, const float* __restrict__ v2,
           float* __restrict__ out)
{
    __shared__ __align__(16) _Float16 in0[8 * SL0];
    __shared__ __align__(16) _Float16 in1[8 * SL1];
    __shared__ __align__(16) _Float16 in2[8 * SL1];
    __shared__ __align__(16) int flags[16];
    __shared__ float fcA[BB * 64];
    __shared__ float fcB[BB * 64];
    __shared__ float fcW[54 * 65];
    __shared__ float fcP[5 * 64];

    const int tid  = threadIdx.x;
    const int wv   = tid >> 6;      // 0..13
    const int role = wv >> 2;       // 0=L2, 1=L1, 2=L0, 3=stager
    const int w4   = wv & 3;
    const int l    = tid & 63;
    const int q    = l >> 4;
    const int l15  = l & 15;
    const int u    = 16 * w4 + l15;
    const int b    = q;
    const int n0   = blockIdx.x * BB;

    for (int i = tid; i < 8 * SL0; i += 896) in0[i] = (_Float16)0.0f;
    for (int i = tid; i < 8 * SL1; i += 896) in1[i] = (_Float16)0.0f;
    for (int i = tid; i < 8 * SL1; i += 896) in2[i] = (_Float16)0.0f;
    if (tid < 16) flags[tid] = (tid >= 14) ? (1 << 29) : -1;

    // ---- weight B-fragments: one unit per wave ----
    half8 wf[4][4];
    float4v biasC[4];
    if (role == 2) {                 // layer 0
#pragma unroll
        for (int g = 0; g < 4; ++g) {
            const int row = 64 * g + u;
#pragma unroll
            for (int kt = 0; kt < 3; ++kt) {
                half8 h{};
#pragma unroll
                for (int j = 0; j < 8; ++j) {
                    const int k = 32 * kt + 8 * q + j;
                    float val = 0.0f;
                    if (k < 32) { if (k < FF) val = Wih0[row * FF + k]; }
                    else        { val = Whh0[row * HH + (k - 32)]; }
                    h[j] = (_Float16)val;
                }
                wf[g][kt] = h;
            }
            float bv = bih0[row] + bhh0[row];
            biasC[g] = float4v{bv, bv, bv, bv};
        }
    } else if (role < 2) {           // 0 -> layer 2, 1 -> layer 1
        const float* Wih = role ? Wih1 : Wih2;
        const float* Whh = role ? Whh1 : Whh2;
        const float* bih = role ? bih1 : bih2;
        const float* bhh = role ? bhh1 : bhh2;
#pragma unroll
        for (int g = 0; g < 4; ++g) {
            const int row = 64 * g + u;
#pragma unroll
            for (int kt = 0; kt < 4; ++kt) {
                half8 h{};
#pragma unroll
                for (int j = 0; j < 8; ++j) {
                    const int k = 32 * kt + 8 * q + j;
                    h[j] = (_Float16)((k < 64) ? Wih[row * HH + k] : Whh[row * HH + (k - 64)]);
                }
                wf[g][kt] = h;
            }
            float bv = bih[row] + bhh[row];
            biasC[g] = float4v{bv, bv, bv, bv};
        }
    }

    // ---- x staging lanes: waves 12-13, 88 items ----
    const int  st  = tid - 768;
    const bool xok = (role == 3) && (st >= 0) && (st < BB * FF);
    const int  xb  = xok ? (st / FF) : 0;
    const int  xf  = xok ? (st - xb * FF) : 0;
    const float* xp = x + ((size_t)(n0 + xb) * FF + xf) * TT;

    volatile int* vfl = (volatile int*)flags;
    __syncthreads();

    const int arow = (role == 2) ? ((l15 & 3) * S0 + q * 8) : ((l15 & 3) * S1 + q * 8);
    float c = 0.f;

    if (role == 3) {                   // ===== stager =====
        float xh = xok ? xp[0] : 0.f;
        for (int k = 0; k < 125; ++k) {
            const int tb = k * 8;
#pragma unroll
            for (int s = 0; s < 8; ++s) {
                const int t = tb + s;
                if ((s & 3) == 0) SPIN(ldmin4(flags + 8) >= t - 5);
                if (xok) in0[s * SL0 + xb * S0 + xf] = (_Float16)xh;
                LFENCE();
                if (l == 0) vfl[12 + (wv - 12)] = t;
                if (xok) xh = xp[(t + 1 < TT) ? (t + 1) : (TT - 1)];
            }
        }
    } else if (role == 2) {            // ===== L0 =====
        for (int k = 0; k < 125; ++k) {
            const int tb = k * 8;
#pragma unroll
            for (int s = 0; s < 8; ++s) {
                const int t = tb + s;
                if ((s & 3) == 0)
                    SPIN(ldmin4(flags + 12) >= t + 3 && ldmin4(flags + 4) >= t - 5);
                const _Float16* rd = in0 + s * SL0;
                // input-half (x, k<32): gated by stager lead, not siblings
                half8 a0 = *(const half8*)(rd + arow);
                const int pre = ldmin4(flags + 8);   // pre-issued sibling check
                float4v acc[4];
#pragma unroll
                for (int g = 0; g < 4; ++g)
                    acc[g] = __builtin_amdgcn_mfma_f32_16x16x32_f16(a0, wf[g][0], biasC[g], 0, 0, 0);
                if (pre < t - 1) SPINF(ldmin4(flags + 8) >= t - 1);
                asm volatile("" ::: "memory");       // rec reads after flag obs.
                half8 a1 = *(const half8*)(rd + arow + 32);
                half8 a2 = *(const half8*)(rd + arow + 64);
#pragma unroll
                for (int g = 0; g < 4; ++g)
                    acc[g] = __builtin_amdgcn_mfma_f32_16x16x32_f16(a1, wf[g][1], acc[g], 0, 0, 0);
#pragma unroll
                for (int g = 0; g < 4; ++g)
                    acc[g] = __builtin_amdgcn_mfma_f32_16x16x32_f16(a2, wf[g][2], acc[g], 0, 0, 0);
                float z[4];
#pragma unroll
                for (int g = 0; g < 4; ++g) z[g] = sel4(acc[g], q);
                float h = gate_update(z, c);
                _Float16 hf = (_Float16)h;
                in0[((s + 1) & 7) * SL0 + b * S0 + 32 + u] = hf; // own rec
                in1[s * SL1 + b * S1 + u]                  = hf; // L1 input
                LFENCE();
                if (l == 0) vfl[8 + w4] = t;
            }
        }
    } else {                            // ===== L1 (role==1) / L2 (role==0) =====
        _Float16* rin  = role ? in1 : in2;
        _Float16* rout = role ? in2 : nullptr;
        const int* pin = role ? (flags + 8) : (flags + 4);  // input producer group
        const int* pow_ = role ? (flags + 4) : (flags + 0); // own group
        for (int k = 0; k < 125; ++k) {
            const int tb = k * 8;
#pragma unroll
            for (int s = 0; s < 8; ++s) {
                const int t = tb + s;
                if ((s & 3) == 0) {
                    if (role) SPIN(ldmin4(pin) >= t + 3 && ldmin4(flags + 0) >= t - 5);
                    else      SPIN(ldmin4(pin) >= t + 3);
                }
                const _Float16* rd = rin + s * SL1;
                // input-half (lower layer h, k<64): gated by 3-tick cross lead
                half8 a0 = *(const half8*)(rd + arow);
                half8 a1 = *(const half8*)(rd + arow + 32);
                const int pre = ldmin4(pow_);        // pre-issued sibling check
                float4v acc[4];
#pragma unroll
                for (int g = 0; g < 4; ++g)
                    acc[g] = __builtin_amdgcn_mfma_f32_16x16x32_f16(a0, wf[g][0], biasC[g], 0, 0, 0);
#pragma unroll
                for (int g = 0; g < 4; ++g)
                    acc[g] = __builtin_amdgcn_mfma_f32_16x16x32_f16(a1, wf[g][1], acc[g], 0, 0, 0);
                if (pre < t - 1) SPINF(ldmin4(pow_) >= t - 1);
                asm volatile("" ::: "memory");       // rec reads after flag obs.
                half8 a2 = *(const half8*)(rd + arow + 64);
                half8 a3 = *(const half8*)(rd + arow + 96);
#pragma unroll
                for (int g = 0; g < 4; ++g)
                    acc[g] = __builtin_amdgcn_mfma_f32_16x16x32_f16(a2, wf[g][2], acc[g], 0, 0, 0);
#pragma unroll
                for (int g = 0; g < 4; ++g)
                    acc[g] = __builtin_amdgcn_mfma_f32_16x16x32_f16(a3, wf[g][3], acc[g], 0, 0, 0);
                float z[4];
#pragma unroll
                for (int g = 0; g < 4; ++g) z[g] = sel4(acc[g], q);
                float h = gate_update(z, c);
                _Float16 hf = (_Float16)h;
                if (role) {
                    rin[((s + 1) & 7) * SL1 + b * S1 + 64 + u] = hf; // own rec
                    rout[s * SL1 + b * S1 + u]                 = hf; // L2 input
                } else {
                    if (t != TT - 1) rin[((s + 1) & 7) * SL1 + b * S1 + 64 + u] = hf;
                    else             fcA[b * 64 + u] = h;            // final h2 (fp32)
                }
                LFENCE();
                if (l == 0) vfl[(role ? 4 : 0) + w4] = t;
            }
        }
    }

    __syncthreads();

    // ================= FC head (fp32) =================
    for (int i = tid; i < 54 * 64; i += 896) fcW[(i >> 6) * 65 + (i & 63)] = w0[i];
    for (int i = tid; i < 54; i += 896) {
        fcP[i] = b0[i]; fcP[64 + i] = g0[i]; fcP[128 + i] = be0[i];
        fcP[192 + i] = m0[i]; fcP[256 + i] = v0[i];
    }
    __syncthreads();
    for (int idx = tid; idx < BB * 54; idx += 896) {
        const int bb = idx / 54, j = idx - bb * 54;
        float s = fcP[j];
        for (int k = 0; k < 64; ++k) s += fcW[j * 65 + k] * fcA[bb * 64 + k];
        s = (s - fcP[192 + j]) * rsqrtf(fcP[256 + j] + 1e-5f) * fcP[64 + j] + fcP[128 + j];
        fcB[bb * 64 + j] = fmaxf(s, 0.0f);
    }
    __syncthreads();

    for (int i = tid; i < 44 * 54; i += 896) fcW[(i / 54) * 55 + (i % 54)] = w1[i];
    for (int i = tid; i < 44; i += 896) {
        fcP[i] = b1[i]; fcP[64 + i] = g1[i]; fcP[128 + i] = be1[i];
        fcP[192 + i] = m1[i]; fcP[256 + i] = v1[i];
    }
    __syncthreads();
    for (int idx = tid; idx < BB * 44; idx += 896) {
        const int bb = idx / 44, j = idx - bb * 44;
        float s = fcP[j];
        for (int k = 0; k < 54; ++k) s += fcW[j * 55 + k] * fcB[bb * 64 + k];
        s = (s - fcP[192 + j]) * rsqrtf(fcP[256 + j] + 1e-5f) * fcP[64 + j] + fcP[128 + j];
        fcA[bb * 64 + j] = fmaxf(s, 0.0f);
    }
    __syncthreads();

    for (int i = tid; i < 24 * 44; i += 896) fcW[(i / 44) * 45 + (i % 44)] = w2[i];
    for (int i = tid; i < 24; i += 896) {
        fcP[i] = b2[i]; fcP[64 + i] = g2[i]; fcP[128 + i] = be2[i];
        fcP[192 + i] = m2[i]; fcP[256 + i] = v2[i];
    }
    __syncthreads();
    for (int idx = tid; idx < BB * 24; idx += 896) {
        const int bb = idx / 24, j = idx - bb * 24;
        float s = fcP[j];
        for (int k = 0; k < 44; ++k) s += fcW[j * 45 + k] * fcA[bb * 64 + k];
        s = (s - fcP[192 + j]) * rsqrtf(fcP[256 + j] + 1e-5f) * fcP[64 + j] + fcP[128 + j];
        fcB[bb * 64 + j] = fmaxf(s, 0.0f);
    }
    __syncthreads();

    for (int i = tid; i < 4 * 24; i += 896) fcW[(i / 24) * 25 + (i % 24)] = w3[i];
    for (int i = tid; i < 4; i += 896) fcP[i] = b3[i];
    __syncthreads();
    for (int idx = tid; idx < BB * 4; idx += 896) {
        const int bb = idx / 4, j = idx - bb * 4;
        float s = fcP[j];
        for (int k = 0; k < 24; ++k) s += fcW[j * 25 + k] * fcB[bb * 64 + k];
        out[(size_t)(n0 + bb) * 4 + j] = s;
    }
}

extern "C" void kernel_launch(void* const* d_in, const int* in_sizes, int n_in,
                              void* d_out, int out_size, void* d_ws, size_t ws_size,
                              hipStream_t stream) {
    const float* p[33];
    for (int i = 0; i < 33; ++i) p[i] = (const float*)d_in[i];
    lstm_fused<<<NBLK, 896, 0, stream>>>(
        p[0],
        p[1], p[2], p[3], p[4],
        p[5], p[6], p[7], p[8],
        p[9], p[10], p[11], p[12],
        p[13], p[14], p[15], p[16], p[17], p[18], p[19], p[20],
        p[21], p[22], p[23], p[24],
        p[25], p[26], p[27], p[28],
        p[29], p[30], p[31], p[32],
        (float*)d_out);
}

// Round 2
// 783.777 us; speedup vs baseline: 1.0455x; 1.0064x over previous
//
#include <hip/hip_runtime.h>
#include <hip/hip_fp16.h>

// N=1024, F=22, T=1000, H=64, gates 4H=256
// R12: replace flag/poll dataflow (R10/R11) with raw s_barrier LOCKSTEP.
//  - One lgkmcnt(0)+s_barrier per tick orders all LDS producer->consumer edges.
//  - All flags, monotone counters, ldmin4 polls, sleeps, threadfences: GONE.
//  - Strict schedule: global tick tau; L0 computes t=tau, L1 t=tau-1, L2 t=tau-2.
//    Stager writes x(tau+1) at tick tau (depth-2 register prefetch).
//  - Slot math (ring 8): writes at tick tau go to slots tau&7 / (tau+1)&7,
//    reads come from slots written at tick tau-1; same-slot writes are
//    column-disjoint (x: cols 0..22, L0rec: 32..96; fwd: 0..64, rec: 64..128).
//    With lockstep (skew 0) overwrite distance >= 6 slots. Audited.
//  - Barrier count identical for all 14 waves: 126*8 = 1008 ticks, guards inside.
// 896 threads = 14 waves: 0-3 L2, 4-7 L1, 8-11 L0, 12-13 x stager.
#define TT 1000
#define FF 22
#define HH 64
#define BB 4
#define NBLK 256
#define S0 112
#define S1 144
#define SL0 (4 * S0)
#define SL1 (4 * S1)

typedef _Float16 half8 __attribute__((ext_vector_type(8)));
typedef float float4v __attribute__((ext_vector_type(4)));

__device__ __forceinline__ float sigm(float v) {
    return __builtin_amdgcn_rcpf(1.0f + __expf(-v));
}
__device__ __forceinline__ float tanh_(float v) {
    return 1.0f - 2.0f * __builtin_amdgcn_rcpf(__expf(2.0f * v) + 1.0f);
}

__device__ __forceinline__ float sel4(const float4v a, int q) {
    float lo = (q & 2) ? a[2] : a[0];
    float hi = (q & 2) ? a[3] : a[1];
    return (q & 1) ? hi : lo;
}

__device__ __forceinline__ float gate_update(const float z[4], float& c) {
    float cc = sigm(z[1]) * c + sigm(z[0]) * tanh_(z[2]);
    c = cc;
    return sigm(z[3]) * tanh_(cc);
}

// producer-side LDS release before barrier (no vmcnt drain needed)
#define LFENCE() asm volatile("s_waitcnt lgkmcnt(0)" ::: "memory")
#define BAR()    __builtin_amdgcn_s_barrier()

extern "C" __global__ void __launch_bounds__(896, 1)
lstm_fused(const float* __restrict__ x,
           const float* __restrict__ Wih0, const float* __restrict__ Whh0,
           const float* __restrict__ bih0, const float* __restrict__ bhh0,
           const float* __restrict__ Wih1, const float* __restrict__ Whh1,
           const float* __restrict__ bih1, const float* __restrict__ bhh1,
           const float* __restrict__ Wih2, const float* __restrict__ Whh2,
           const float* __restrict__ bih2, const float* __restrict__ bhh2,
           const float* __restrict__ w0, const float* __restrict__ b0,
           const float* __restrict__ w1, const float* __restrict__ b1,
           const float* __restrict__ w2, const float* __restrict__ b2,
           const float* __restrict__ w3, const float* __restrict__ b3,
           const float* __restrict__ g0, const float* __restrict__ be0,
           const float* __restrict__ m0, const float* __restrict__ v0,
           const float* __restrict__ g1, const float* __restrict__ be1,
           const float* __restrict__ m1, const float* __restrict__ v1,
           const float* __restrict__ g2, const float* __restrict__ be2,
           const float* __restrict__ m2, const float* __restrict__ v2,
           float* __restrict__ out)
{
    __shared__ __align__(16) _Float16 in0[8 * SL0];
    __shared__ __align__(16) _Float16 in1[8 * SL1];
    __shared__ __align__(16) _Float16 in2[8 * SL1];
    __shared__ float fcA[BB * 64];
    __shared__ float fcB[BB * 64];
    __shared__ float fcW[54 * 65];
    __shared__ float fcP[5 * 64];

    const int tid  = threadIdx.x;
    const int wv   = tid >> 6;      // 0..13
    const int role = wv >> 2;       // 0=L2, 1=L1, 2=L0, 3=stager
    const int w4   = wv & 3;
    const int l    = tid & 63;
    const int q    = l >> 4;
    const int l15  = l & 15;
    const int u    = 16 * w4 + l15;
    const int b    = q;
    const int n0   = blockIdx.x * BB;

    for (int i = tid; i < 8 * SL0; i += 896) in0[i] = (_Float16)0.0f;
    for (int i = tid; i < 8 * SL1; i += 896) in1[i] = (_Float16)0.0f;
    for (int i = tid; i < 8 * SL1; i += 896) in2[i] = (_Float16)0.0f;

    // ---- weight B-fragments: one unit per wave ----
    half8 wf[4][4];
    float4v biasC[4];
    if (role == 2) {                 // layer 0
#pragma unroll
        for (int g = 0; g < 4; ++g) {
            const int row = 64 * g + u;
#pragma unroll
            for (int kt = 0; kt < 3; ++kt) {
                half8 h{};
#pragma unroll
                for (int j = 0; j < 8; ++j) {
                    const int k = 32 * kt + 8 * q + j;
                    float val = 0.0f;
                    if (k < 32) { if (k < FF) val = Wih0[row * FF + k]; }
                    else        { val = Whh0[row * HH + (k - 32)]; }
                    h[j] = (_Float16)val;
                }
                wf[g][kt] = h;
            }
            float bv = bih0[row] + bhh0[row];
            biasC[g] = float4v{bv, bv, bv, bv};
        }
    } else if (role < 2) {           // 0 -> layer 2, 1 -> layer 1
        const float* Wih = role ? Wih1 : Wih2;
        const float* Whh = role ? Whh1 : Whh2;
        const float* bih = role ? bih1 : bih2;
        const float* bhh = role ? bhh1 : bhh2;
#pragma unroll
        for (int g = 0; g < 4; ++g) {
            const int row = 64 * g + u;
#pragma unroll
            for (int kt = 0; kt < 4; ++kt) {
                half8 h{};
#pragma unroll
                for (int j = 0; j < 8; ++j) {
                    const int k = 32 * kt + 8 * q + j;
                    h[j] = (_Float16)((k < 64) ? Wih[row * HH + k] : Whh[row * HH + (k - 64)]);
                }
                wf[g][kt] = h;
            }
            float bv = bih[row] + bhh[row];
            biasC[g] = float4v{bv, bv, bv, bv};
        }
    }

    // ---- x staging lanes: waves 12-13, 88 items ----
    const int  st  = tid - 768;
    const bool xok = (role == 3) && (st >= 0) && (st < BB * FF);
    const int  xb  = xok ? (st / FF) : 0;
    const int  xf  = xok ? (st - xb * FF) : 0;
    const float* xp = x + ((size_t)(n0 + xb) * FF + xf) * TT;

    __syncthreads();                 // zero-init complete before pre-stage

    // pre-stage x(0) into slot 0; ordered by first in-loop LFENCE+BAR
    if (xok) in0[0 * SL0 + xb * S0 + xf] = (_Float16)xp[0];
    float xA = xok ? xp[1] : 0.f;    // value to write at tau=0 (timestep 1)
    float xB = xok ? xp[2] : 0.f;    // depth-2 prefetch

    const int arow = (role == 2) ? ((l15 & 3) * S0 + q * 8) : ((l15 & 3) * S1 + q * 8);
    float c = 0.f;

    // ================= lockstep main loop: 126*8 = 1008 ticks =================
    for (int k = 0; k < 126; ++k) {
#pragma unroll
        for (int s = 0; s < 8; ++s) {
            const int tau = 8 * k + s;
            LFENCE();                // my writes from previous tick visible
            BAR();                   // all waves aligned at tick tau

            if (role == 3) {         // ===== stager: write x(tau+1) =====
                if (tau <= TT - 2) {
                    if (xok) in0[((s + 1) & 7) * SL0 + xb * S0 + xf] = (_Float16)xA;
                    xA = xB;
                    if (xok) {
                        int tn = tau + 3; if (tn > TT - 1) tn = TT - 1;
                        xB = xp[tn];
                    }
                }
            } else if (role == 2) {  // ===== L0: t = tau =====
                if (tau <= TT - 1) {
                    const _Float16* rd = in0 + s * SL0;
                    half8 a0 = *(const half8*)(rd + arow);
                    half8 a1 = *(const half8*)(rd + arow + 32);
                    half8 a2 = *(const half8*)(rd + arow + 64);
                    float4v acc[4];
#pragma unroll
                    for (int g = 0; g < 4; ++g)
                        acc[g] = __builtin_amdgcn_mfma_f32_16x16x32_f16(a0, wf[g][0], biasC[g], 0, 0, 0);
#pragma unroll
                    for (int g = 0; g < 4; ++g)
                        acc[g] = __builtin_amdgcn_mfma_f32_16x16x32_f16(a1, wf[g][1], acc[g], 0, 0, 0);
#pragma unroll
                    for (int g = 0; g < 4; ++g)
                        acc[g] = __builtin_amdgcn_mfma_f32_16x16x32_f16(a2, wf[g][2], acc[g], 0, 0, 0);
                    float z[4];
#pragma unroll
                    for (int g = 0; g < 4; ++g) z[g] = sel4(acc[g], q);
                    float h = gate_update(z, c);
                    _Float16 hf = (_Float16)h;
                    in0[((s + 1) & 7) * SL0 + b * S0 + 32 + u] = hf; // rec -> slot tau+1
                    in1[s * SL1 + b * S1 + u]                  = hf; // fwd -> slot tau
                }
            } else if (role == 1) {  // ===== L1: t = tau-1 =====
                if (tau >= 1 && tau <= TT) {
                    const int sr = (s + 7) & 7;           // (tau-1)&7
                    const _Float16* rd = in1 + sr * SL1;
                    half8 a0 = *(const half8*)(rd + arow);
                    half8 a1 = *(const half8*)(rd + arow + 32);
                    half8 a2 = *(const half8*)(rd + arow + 64);
                    half8 a3 = *(const half8*)(rd + arow + 96);
                    float4v acc[4];
#pragma unroll
                    for (int g = 0; g < 4; ++g)
                        acc[g] = __builtin_amdgcn_mfma_f32_16x16x32_f16(a0, wf[g][0], biasC[g], 0, 0, 0);
#pragma unroll
                    for (int g = 0; g < 4; ++g)
                        acc[g] = __builtin_amdgcn_mfma_f32_16x16x32_f16(a1, wf[g][1], acc[g], 0, 0, 0);
#pragma unroll
                    for (int g = 0; g < 4; ++g)
                        acc[g] = __builtin_amdgcn_mfma_f32_16x16x32_f16(a2, wf[g][2], acc[g], 0, 0, 0);
#pragma unroll
                    for (int g = 0; g < 4; ++g)
                        acc[g] = __builtin_amdgcn_mfma_f32_16x16x32_f16(a3, wf[g][3], acc[g], 0, 0, 0);
                    float z[4];
#pragma unroll
                    for (int g = 0; g < 4; ++g) z[g] = sel4(acc[g], q);
                    float h = gate_update(z, c);
                    _Float16 hf = (_Float16)h;
                    in1[s * SL1 + b * S1 + 64 + u] = hf;  // rec -> slot tau ( = (t+1)&7 )
                    in2[sr * SL1 + b * S1 + u]     = hf;  // fwd -> slot t&7
                }
            } else {                 // ===== L2: t = tau-2 =====
                if (tau >= 2 && tau <= TT + 1) {
                    const int sr = (s + 6) & 7;           // (tau-2)&7
                    const _Float16* rd = in2 + sr * SL1;
                    half8 a0 = *(const half8*)(rd + arow);
                    half8 a1 = *(const half8*)(rd + arow + 32);
                    half8 a2 = *(const half8*)(rd + arow + 64);
                    half8 a3 = *(const half8*)(rd + arow + 96);
                    float4v acc[4];
#pragma unroll
                    for (int g = 0; g < 4; ++g)
                        acc[g] = __builtin_amdgcn_mfma_f32_16x16x32_f16(a0, wf[g][0], biasC[g], 0, 0, 0);
#pragma unroll
                    for (int g = 0; g < 4; ++g)
                        acc[g] = __builtin_amdgcn_mfma_f32_16x16x32_f16(a1, wf[g][1], acc[g], 0, 0, 0);
#pragma unroll
                    for (int g = 0; g < 4; ++g)
                        acc[g] = __builtin_amdgcn_mfma_f32_16x16x32_f16(a2, wf[g][2], acc[g], 0, 0, 0);
#pragma unroll
                    for (int g = 0; g < 4; ++g)
                        acc[g] = __builtin_amdgcn_mfma_f32_16x16x32_f16(a3, wf[g][3], acc[g], 0, 0, 0);
                    float z[4];
#pragma unroll
                    for (int g = 0; g < 4; ++g) z[g] = sel4(acc[g], q);
                    float h = gate_update(z, c);
                    if (tau != TT + 1) {
                        in2[((s + 7) & 7) * SL1 + b * S1 + 64 + u] = (_Float16)h; // rec -> slot (t+1)&7
                    } else {
                        fcA[b * 64 + u] = h;              // final h2(999), fp32
                    }
                }
            }
        }
    }

    __syncthreads();

    // ================= FC head (fp32) =================
    for (int i = tid; i < 54 * 64; i += 896) fcW[(i >> 6) * 65 + (i & 63)] = w0[i];
    for (int i = tid; i < 54; i += 896) {
        fcP[i] = b0[i]; fcP[64 + i] = g0[i]; fcP[128 + i] = be0[i];
        fcP[192 + i] = m0[i]; fcP[256 + i] = v0[i];
    }
    __syncthreads();
    for (int idx = tid; idx < BB * 54; idx += 896) {
        const int bb = idx / 54, j = idx - bb * 54;
        float s = fcP[j];
        for (int k = 0; k < 64; ++k) s += fcW[j * 65 + k] * fcA[bb * 64 + k];
        s = (s - fcP[192 + j]) * rsqrtf(fcP[256 + j] + 1e-5f) * fcP[64 + j] + fcP[128 + j];
        fcB[bb * 64 + j] = fmaxf(s, 0.0f);
    }
    __syncthreads();

    for (int i = tid; i < 44 * 54; i += 896) fcW[(i / 54) * 55 + (i % 54)] = w1[i];
    for (int i = tid; i < 44; i += 896) {
        fcP[i] = b1[i]; fcP[64 + i] = g1[i]; fcP[128 + i] = be1[i];
        fcP[192 + i] = m1[i]; fcP[256 + i] = v1[i];
    }
    __syncthreads();
    for (int idx = tid; idx < BB * 44; idx += 896) {
        const int bb = idx / 44, j = idx - bb * 44;
        float s = fcP[j];
        for (int k = 0; k < 54; ++k) s += fcW[j * 55 + k] * fcB[bb * 64 + k];
        s = (s - fcP[192 + j]) * rsqrtf(fcP[256 + j] + 1e-5f) * fcP[64 + j] + fcP[128 + j];
        fcA[bb * 64 + j] = fmaxf(s, 0.0f);
    }
    __syncthreads();

    for (int i = tid; i < 24 * 44; i += 896) fcW[(i / 44) * 45 + (i % 44)] = w2[i];
    for (int i = tid; i < 24; i += 896) {
        fcP[i] = b2[i]; fcP[64 + i] = g2[i]; fcP[128 + i] = be2[i];
        fcP[192 + i] = m2[i]; fcP[256 + i] = v2[i];
    }
    __syncthreads();
    for (int idx = tid; idx < BB * 24; idx += 896) {
        const int bb = idx / 24, j = idx - bb * 24;
        float s = fcP[j];
        for (int k = 0; k < 44; ++k) s += fcW[j * 45 + k] * fcA[bb * 64 + k];
        s = (s - fcP[192 + j]) * rsqrtf(fcP[256 + j] + 1e-5f) * fcP[64 + j] + fcP[128 + j];
        fcB[bb * 64 + j] = fmaxf(s, 0.0f);
    }
    __syncthreads();

    for (int i = tid; i < 4 * 24; i += 896) fcW[(i / 24) * 25 + (i % 24)] = w3[i];
    for (int i = tid; i < 4; i += 896) fcP[i] = b3[i];
    __syncthreads();
    for (int idx = tid; idx < BB * 4; idx += 896) {
        const int bb = idx / 4, j = idx - bb * 4;
        float s = fcP[j];
        for (int k = 0; k < 24; ++k) s += fcW[j * 25 + k] * fcB[bb * 64 + k];
        out[(size_t)(n0 + bb) * 4 + j] = s;
    }
}

extern "C" void kernel_launch(void* const* d_in, const int* in_sizes, int n_in,
                              void* d_out, int out_size, void* d_ws, size_t ws_size,
                              hipStream_t stream) {
    const float* p[33];
    for (int i = 0; i < 33; ++i) p[i] = (const float*)d_in[i];
    lstm_fused<<<NBLK, 896, 0, stream>>>(
        p[0],
        p[1], p[2], p[3], p[4],
        p[5], p[6], p[7], p[8],
        p[9], p[10], p[11], p[12],
        p[13], p[14], p[15], p[16], p[17], p[18], p[19], p[20],
        p[21], p[22], p[23], p[24],
        p[25], p[26], p[27], p[28],
        p[29], p[30], p[31], p[32],
        (float*)d_out);
}

// Round 3
// 779.795 us; speedup vs baseline: 1.0508x; 1.0051x over previous
//
#include <hip/hip_runtime.h>
#include <hip/hip_fp16.h>

// N=1024, F=22, T=1000, H=64, gates 4H=256
// R13: R12 barrier-lockstep + convoy-breaking + cheaper gates.
//  - Static per-role s_setprio (L0=3, L1=2, L2=1, ST=0): strict issue priority
//    drains one wave's MFMAs back-to-back, staggering matrix-pipe exit so each
//    wave's gate VALU overlaps the other waves' MFMAs (R12 showed sum, not max:
//    785 cy MFMA + 898 cy VALU = 1721 cy tick, zero overlap from fair RR).
//  - Fused-denominator gates: sig(a)*tanh(b) = (e^{2b}-1)/((1+e^-a)(1+e^{2b}));
//    f-gate and i*g share one rcp. 10 -> 7 transcendentals per gate_update.
//    Exact hw exp/rcp (no poly approx); |z| << 88 so no overflow path.
// Structure (unchanged from R12): one lgkmcnt(0)+s_barrier per tick; strict
// schedule L0 t=tau, L1 t=tau-1, L2 t=tau-2; stager writes x(tau+1); ring-8
// slot math audited in R12. 896 thr = 14 waves: 0-3 L2, 4-7 L1, 8-11 L0,
// 12-13 stager.
#define TT 1000
#define FF 22
#define HH 64
#define BB 4
#define NBLK 256
#define S0 112
#define S1 144
#define SL0 (4 * S0)
#define SL1 (4 * S1)

typedef _Float16 half8 __attribute__((ext_vector_type(8)));
typedef float float4v __attribute__((ext_vector_type(4)));

__device__ __forceinline__ float sel4(const float4v a, int q) {
    float lo = (q & 2) ? a[2] : a[0];
    float hi = (q & 2) ? a[3] : a[1];
    return (q & 1) ? hi : lo;
}

// Fused LSTM gate math: 5 exp + 2 rcp (was 5 exp + 5 rcp).
//  f      = sigm(z1) = 1/d1,              d1 = 1+e^{-z1}
//  i*g    = sigm(z0)*tanh(z2) = (e2-1)/d2, d2 = (1+e^{-z0})(1+e2), e2=e^{2 z2}
//  shared r = rcp(d1*d2):  f = d2*r,  i*g = (e2-1)*d1*r
//  h      = sigm(z3)*tanh(cc) = (e4-1)*rcp((1+e^{-z3})(1+e4)),   e4=e^{2 cc}
__device__ __forceinline__ float gate_fused(const float z[4], float& c) {
    float e0 = __expf(-z[0]);
    float e1 = __expf(-z[1]);
    float e2 = __expf(2.0f * z[2]);
    float d1 = 1.0f + e1;
    float d2 = (1.0f + e0) * (1.0f + e2);
    float r  = __builtin_amdgcn_rcpf(d1 * d2);
    float f  = d2 * r;
    float ig = (e2 - 1.0f) * (d1 * r);
    float cc = __builtin_fmaf(f, c, ig);
    c = cc;
    float e3 = __expf(-z[3]);
    float e4 = __expf(2.0f * cc);
    float r2 = __builtin_amdgcn_rcpf((1.0f + e3) * (1.0f + e4));
    return (e4 - 1.0f) * r2;
}

// producer-side LDS release before barrier (no vmcnt drain needed)
#define LFENCE() asm volatile("s_waitcnt lgkmcnt(0)" ::: "memory")
#define BAR()    __builtin_amdgcn_s_barrier()

extern "C" __global__ void __launch_bounds__(896, 1)
lstm_fused(const float* __restrict__ x,
           const float* __restrict__ Wih0, const float* __restrict__ Whh0,
           const float* __restrict__ bih0, const float* __restrict__ bhh0,
           const float* __restrict__ Wih1, const float* __restrict__ Whh1,
           const float* __restrict__ bih1, const float* __restrict__ bhh1,
           const float* __restrict__ Wih2, const float* __restrict__ Whh2,
           const float* __restrict__ bih2, const float* __restrict__ bhh2,
           const float* __restrict__ w0, const float* __restrict__ b0,
           const float* __restrict__ w1, const float* __restrict__ b1,
           const float* __restrict__ w2, const float* __restrict__ b2,
           const float* __restrict__ w3, const float* __restrict__ b3,
           const float* __restrict__ g0, const float* __restrict__ be0,
           const float* __restrict__ m0, const float* __restrict__ v0,
           const float* __restrict__ g1, const float* __restrict__ be1,
           const float* __restrict__ m1, const float* __restrict__ v1,
           const float* __restrict__ g2, const float* __restrict__ be2,
           const float* __restrict__ m2, const float* __restrict__ v2,
           float* __restrict__ out)
{
    __shared__ __align__(16) _Float16 in0[8 * SL0];
    __shared__ __align__(16) _Float16 in1[8 * SL1];
    __shared__ __align__(16) _Float16 in2[8 * SL1];
    __shared__ float fcA[BB * 64];
    __shared__ float fcB[BB * 64];
    __shared__ float fcW[54 * 65];
    __shared__ float fcP[5 * 64];

    const int tid  = threadIdx.x;
    const int wv   = tid >> 6;      // 0..13
    const int role = wv >> 2;       // 0=L2, 1=L1, 2=L0, 3=stager
    const int w4   = wv & 3;
    const int l    = tid & 63;
    const int q    = l >> 4;
    const int l15  = l & 15;
    const int u    = 16 * w4 + l15;
    const int b    = q;
    const int n0   = blockIdx.x * BB;

    for (int i = tid; i < 8 * SL0; i += 896) in0[i] = (_Float16)0.0f;
    for (int i = tid; i < 8 * SL1; i += 896) in1[i] = (_Float16)0.0f;
    for (int i = tid; i < 8 * SL1; i += 896) in2[i] = (_Float16)0.0f;

    // ---- weight B-fragments: one unit per wave ----
    half8 wf[4][4];
    float4v biasC[4];
    if (role == 2) {                 // layer 0
#pragma unroll
        for (int g = 0; g < 4; ++g) {
            const int row = 64 * g + u;
#pragma unroll
            for (int kt = 0; kt < 3; ++kt) {
                half8 h{};
#pragma unroll
                for (int j = 0; j < 8; ++j) {
                    const int k = 32 * kt + 8 * q + j;
                    float val = 0.0f;
                    if (k < 32) { if (k < FF) val = Wih0[row * FF + k]; }
                    else        { val = Whh0[row * HH + (k - 32)]; }
                    h[j] = (_Float16)val;
                }
                wf[g][kt] = h;
            }
            float bv = bih0[row] + bhh0[row];
            biasC[g] = float4v{bv, bv, bv, bv};
        }
    } else if (role < 2) {           // 0 -> layer 2, 1 -> layer 1
        const float* Wih = role ? Wih1 : Wih2;
        const float* Whh = role ? Whh1 : Whh2;
        const float* bih = role ? bih1 : bih2;
        const float* bhh = role ? bhh1 : bhh2;
#pragma unroll
        for (int g = 0; g < 4; ++g) {
            const int row = 64 * g + u;
#pragma unroll
            for (int kt = 0; kt < 4; ++kt) {
                half8 h{};
#pragma unroll
                for (int j = 0; j < 8; ++j) {
                    const int k = 32 * kt + 8 * q + j;
                    h[j] = (_Float16)((k < 64) ? Wih[row * HH + k] : Whh[row * HH + (k - 64)]);
                }
                wf[g][kt] = h;
            }
            float bv = bih[row] + bhh[row];
            biasC[g] = float4v{bv, bv, bv, bv};
        }
    }

    // ---- x staging lanes: waves 12-13, 88 items ----
    const int  st  = tid - 768;
    const bool xok = (role == 3) && (st >= 0) && (st < BB * FF);
    const int  xb  = xok ? (st / FF) : 0;
    const int  xf  = xok ? (st - xb * FF) : 0;
    const float* xp = x + ((size_t)(n0 + xb) * FF + xf) * TT;

    __syncthreads();                 // zero-init complete before pre-stage

    // pre-stage x(0) into slot 0; ordered by first in-loop LFENCE+BAR
    if (xok) in0[0 * SL0 + xb * S0 + xf] = (_Float16)xp[0];
    float xA = xok ? xp[1] : 0.f;    // value to write at tau=0 (timestep 1)
    float xB = xok ? xp[2] : 0.f;    // depth-2 prefetch

    const int arow = (role == 2) ? ((l15 & 3) * S0 + q * 8) : ((l15 & 3) * S1 + q * 8);
    float c = 0.f;

    // ---- convoy-breaking: strict per-role issue priority (wave-uniform) ----
    // L0 highest -> drains its 12 MFMAs first, runs gates under L1/L2 MFMAs;
    // L2 lowest -> fills the matrix pipe tail. Stager stays at 0.
    if (role == 2)      __builtin_amdgcn_s_setprio(3);
    else if (role == 1) __builtin_amdgcn_s_setprio(2);
    else if (role == 0) __builtin_amdgcn_s_setprio(1);

    // ================= lockstep main loop: 126*8 = 1008 ticks =================
    for (int k = 0; k < 126; ++k) {
#pragma unroll
        for (int s = 0; s < 8; ++s) {
            const int tau = 8 * k + s;
            LFENCE();                // my writes from previous tick visible
            BAR();                   // all waves aligned at tick tau

            if (role == 3) {         // ===== stager: write x(tau+1) =====
                if (tau <= TT - 2) {
                    if (xok) in0[((s + 1) & 7) * SL0 + xb * S0 + xf] = (_Float16)xA;
                    xA = xB;
                    if (xok) {
                        int tn = tau + 3; if (tn > TT - 1) tn = TT - 1;
                        xB = xp[tn];
                    }
                }
            } else if (role == 2) {  // ===== L0: t = tau =====
                if (tau <= TT - 1) {
                    const _Float16* rd = in0 + s * SL0;
                    half8 a0 = *(const half8*)(rd + arow);
                    half8 a1 = *(const half8*)(rd + arow + 32);
                    half8 a2 = *(const half8*)(rd + arow + 64);
                    float4v acc[4];
#pragma unroll
                    for (int g = 0; g < 4; ++g)
                        acc[g] = __builtin_amdgcn_mfma_f32_16x16x32_f16(a0, wf[g][0], biasC[g], 0, 0, 0);
#pragma unroll
                    for (int g = 0; g < 4; ++g)
                        acc[g] = __builtin_amdgcn_mfma_f32_16x16x32_f16(a1, wf[g][1], acc[g], 0, 0, 0);
#pragma unroll
                    for (int g = 0; g < 4; ++g)
                        acc[g] = __builtin_amdgcn_mfma_f32_16x16x32_f16(a2, wf[g][2], acc[g], 0, 0, 0);
                    float z[4];
#pragma unroll
                    for (int g = 0; g < 4; ++g) z[g] = sel4(acc[g], q);
                    float h = gate_fused(z, c);
                    _Float16 hf = (_Float16)h;
                    in0[((s + 1) & 7) * SL0 + b * S0 + 32 + u] = hf; // rec -> slot tau+1
                    in1[s * SL1 + b * S1 + u]                  = hf; // fwd -> slot tau
                }
            } else if (role == 1) {  // ===== L1: t = tau-1 =====
                if (tau >= 1 && tau <= TT) {
                    const int sr = (s + 7) & 7;           // (tau-1)&7
                    const _Float16* rd = in1 + sr * SL1;
                    half8 a0 = *(const half8*)(rd + arow);
                    half8 a1 = *(const half8*)(rd + arow + 32);
                    half8 a2 = *(const half8*)(rd + arow + 64);
                    half8 a3 = *(const half8*)(rd + arow + 96);
                    float4v acc[4];
#pragma unroll
                    for (int g = 0; g < 4; ++g)
                        acc[g] = __builtin_amdgcn_mfma_f32_16x16x32_f16(a0, wf[g][0], biasC[g], 0, 0, 0);
#pragma unroll
                    for (int g = 0; g < 4; ++g)
                        acc[g] = __builtin_amdgcn_mfma_f32_16x16x32_f16(a1, wf[g][1], acc[g], 0, 0, 0);
#pragma unroll
                    for (int g = 0; g < 4; ++g)
                        acc[g] = __builtin_amdgcn_mfma_f32_16x16x32_f16(a2, wf[g][2], acc[g], 0, 0, 0);
#pragma unroll
                    for (int g = 0; g < 4; ++g)
                        acc[g] = __builtin_amdgcn_mfma_f32_16x16x32_f16(a3, wf[g][3], acc[g], 0, 0, 0);
                    float z[4];
#pragma unroll
                    for (int g = 0; g < 4; ++g) z[g] = sel4(acc[g], q);
                    float h = gate_fused(z, c);
                    _Float16 hf = (_Float16)h;
                    in1[s * SL1 + b * S1 + 64 + u] = hf;  // rec -> slot tau ( = (t+1)&7 )
                    in2[sr * SL1 + b * S1 + u]     = hf;  // fwd -> slot t&7
                }
            } else {                 // ===== L2: t = tau-2 =====
                if (tau >= 2 && tau <= TT + 1) {
                    const int sr = (s + 6) & 7;           // (tau-2)&7
                    const _Float16* rd = in2 + sr * SL1;
                    half8 a0 = *(const half8*)(rd + arow);
                    half8 a1 = *(const half8*)(rd + arow + 32);
                    half8 a2 = *(const half8*)(rd + arow + 64);
                    half8 a3 = *(const half8*)(rd + arow + 96);
                    float4v acc[4];
#pragma unroll
                    for (int g = 0; g < 4; ++g)
                        acc[g] = __builtin_amdgcn_mfma_f32_16x16x32_f16(a0, wf[g][0], biasC[g], 0, 0, 0);
#pragma unroll
                    for (int g = 0; g < 4; ++g)
                        acc[g] = __builtin_amdgcn_mfma_f32_16x16x32_f16(a1, wf[g][1], acc[g], 0, 0, 0);
#pragma unroll
                    for (int g = 0; g < 4; ++g)
                        acc[g] = __builtin_amdgcn_mfma_f32_16x16x32_f16(a2, wf[g][2], acc[g], 0, 0, 0);
#pragma unroll
                    for (int g = 0; g < 4; ++g)
                        acc[g] = __builtin_amdgcn_mfma_f32_16x16x32_f16(a3, wf[g][3], acc[g], 0, 0, 0);
                    float z[4];
#pragma unroll
                    for (int g = 0; g < 4; ++g) z[g] = sel4(acc[g], q);
                    float h = gate_fused(z, c);
                    if (tau != TT + 1) {
                        in2[((s + 7) & 7) * SL1 + b * S1 + 64 + u] = (_Float16)h; // rec -> slot (t+1)&7
                    } else {
                        fcA[b * 64 + u] = h;              // final h2(999), fp32
                    }
                }
            }
        }
    }

    __builtin_amdgcn_s_setprio(0);
    __syncthreads();

    // ================= FC head (fp32) =================
    for (int i = tid; i < 54 * 64; i += 896) fcW[(i >> 6) * 65 + (i & 63)] = w0[i];
    for (int i = tid; i < 54; i += 896) {
        fcP[i] = b0[i]; fcP[64 + i] = g0[i]; fcP[128 + i] = be0[i];
        fcP[192 + i] = m0[i]; fcP[256 + i] = v0[i];
    }
    __syncthreads();
    for (int idx = tid; idx < BB * 54; idx += 896) {
        const int bb = idx / 54, j = idx - bb * 54;
        float s = fcP[j];
        for (int k = 0; k < 64; ++k) s += fcW[j * 65 + k] * fcA[bb * 64 + k];
        s = (s - fcP[192 + j]) * rsqrtf(fcP[256 + j] + 1e-5f) * fcP[64 + j] + fcP[128 + j];
        fcB[bb * 64 + j] = fmaxf(s, 0.0f);
    }
    __syncthreads();

    for (int i = tid; i < 44 * 54; i += 896) fcW[(i / 54) * 55 + (i % 54)] = w1[i];
    for (int i = tid; i < 44; i += 896) {
        fcP[i] = b1[i]; fcP[64 + i] = g1[i]; fcP[128 + i] = be1[i];
        fcP[192 + i] = m1[i]; fcP[256 + i] = v1[i];
    }
    __syncthreads();
    for (int idx = tid; idx < BB * 44; idx += 896) {
        const int bb = idx / 44, j = idx - bb * 44;
        float s = fcP[j];
        for (int k = 0; k < 54; ++k) s += fcW[j * 55 + k] * fcB[bb * 64 + k];
        s = (s - fcP[192 + j]) * rsqrtf(fcP[256 + j] + 1e-5f) * fcP[64 + j] + fcP[128 + j];
        fcA[bb * 64 + j] = fmaxf(s, 0.0f);
    }
    __syncthreads();

    for (int i = tid; i < 24 * 44; i += 896) fcW[(i / 44) * 45 + (i % 44)] = w2[i];
    for (int i = tid; i < 24; i += 896) {
        fcP[i] = b2[i]; fcP[64 + i] = g2[i]; fcP[128 + i] = be2[i];
        fcP[192 + i] = m2[i]; fcP[256 + i] = v2[i];
    }
    __syncthreads();
    for (int idx = tid; idx < BB * 24; idx += 896) {
        const int bb = idx / 24, j = idx - bb * 24;
        float s = fcP[j];
        for (int k = 0; k < 44; ++k) s += fcW[j * 45 + k] * fcA[bb * 64 + k];
        s = (s - fcP[192 + j]) * rsqrtf(fcP[256 + j] + 1e-5f) * fcP[64 + j] + fcP[128 + j];
        fcB[bb * 64 + j] = fmaxf(s, 0.0f);
    }
    __syncthreads();

    for (int i = tid; i < 4 * 24; i += 896) fcW[(i / 24) * 25 + (i % 24)] = w3[i];
    for (int i = tid; i < 4; i += 896) fcP[i] = b3[i];
    __syncthreads();
    for (int idx = tid; idx < BB * 4; idx += 896) {
        const int bb = idx / 4, j = idx - bb * 4;
        float s = fcP[j];
        for (int k = 0; k < 24; ++k) s += fcW[j * 25 + k] * fcB[bb * 64 + k];
        out[(size_t)(n0 + bb) * 4 + j] = s;
    }
}

extern "C" void kernel_launch(void* const* d_in, const int* in_sizes, int n_in,
                              void* d_out, int out_size, void* d_ws, size_t ws_size,
                              hipStream_t stream) {
    const float* p[33];
    for (int i = 0; i < 33; ++i) p[i] = (const float*)d_in[i];
    lstm_fused<<<NBLK, 896, 0, stream>>>(
        p[0],
        p[1], p[2], p[3], p[4],
        p[5], p[6], p[7], p[8],
        p[9], p[10], p[11], p[12],
        p[13], p[14], p[15], p[16], p[17], p[18], p[19], p[20],
        p[21], p[22], p[23], p[24],
        p[25], p[26], p[27], p[28],
        p[29], p[30], p[31], p[32],
        (float*)d_out);
}